// Round 18
// baseline (216.316 us; speedup 1.0000x reference)
//
#include <hip/hip_runtime.h>
#include <hip/hip_fp16.h>
#include <math.h>
#include <stdint.h>

#define NEG 0.2f
#define CSHIFT 9
#define BUCKN (1 << CSHIFT)     // 512 nodes per coarse bucket
#define MAXNB 256               // NB <= 256 for n <= 131072 (CSHIFT=9)
#define CHUNK 4096
#define FBUF 9216               // staged colsrc quarter (mean 8184 @ n=100k/E=6.4M)

// ============================ node transform (packed 32B rows: 8 fp16 h | fp32 alpha_s | pad) ============================

__global__ __launch_bounds__(256) void k1_node(const float* __restrict__ x,
    const float* __restrict__ W1, const float* __restrict__ a1s, const float* __restrict__ a1d,
    float4* __restrict__ h1pk, float* __restrict__ ad1, int n)
{
    __shared__ float wt[8 * 128];
    __shared__ float av[16];
    for (int i = threadIdx.x; i < 1024; i += 256) {
        int r = i >> 3, k = i & 7;
        wt[k * 128 + r] = W1[i];
    }
    if (threadIdx.x < 8)        av[threadIdx.x] = a1s[threadIdx.x];
    else if (threadIdx.x < 16)  av[threadIdx.x] = a1d[threadIdx.x - 8];
    __syncthreads();

    int lane = threadIdx.x & 31;
    int node = blockIdx.x * 8 + (threadIdx.x >> 5);
    if (node >= n) return;

    float4 xv = ((const float4*)(x + (size_t)node * 128))[lane];
    float p[8];
#pragma unroll
    for (int k = 0; k < 8; ++k) {
        float4 wv = ((const float4*)(wt + k * 128))[lane];
        p[k] = xv.x * wv.x + xv.y * wv.y + xv.z * wv.z + xv.w * wv.w;
    }
#pragma unroll
    for (int off = 16; off; off >>= 1)
#pragma unroll
        for (int k = 0; k < 8; ++k) p[k] += __shfl_down(p[k], off, 32);

    if (lane == 0) {
        float s = 0.f, d = 0.f;
        union { float4 f; __half2 h[4]; } u;
#pragma unroll
        for (int k = 0; k < 8; ++k) {
            s += p[k] * av[k];
            d += p[k] * av[8 + k];
        }
#pragma unroll
        for (int q = 0; q < 4; ++q) u.h[q] = __floats2half2_rn(p[2 * q], p[2 * q + 1]);
        h1pk[2 * (size_t)node]     = u.f;                        // 16B fp16 h row
        h1pk[2 * (size_t)node + 1] = make_float4(s, 0.f, 0.f, 0.f);  // alpha_s
        ad1[node] = d;
    }
}

// ============================ bucket-sort CSR build (all-parallel, atomic-free) ============================

__global__ __launch_bounds__(256) void p1a(const int* __restrict__ dst, int* __restrict__ gmat,
                                           int E, int NB)
{
    __shared__ int h[MAXNB];
    for (int i = threadIdx.x; i < NB; i += 256) h[i] = 0;
    __syncthreads();
    int base = blockIdx.x * CHUNK;
    int end = base + CHUNK; if (end > E) end = E;
    for (int i = base + threadIdx.x; i < end; i += 256)
        atomicAdd(&h[dst[i] >> CSHIFT], 1);
    __syncthreads();
    int* row = gmat + (size_t)blockIdx.x * NB;
    for (int i = threadIdx.x; i < NB; i += 256) row[i] = h[i];
}

__global__ __launch_bounds__(256) void pcol(const int* __restrict__ gmat, int* __restrict__ pbaseRel,
    int* __restrict__ total, int NBLK, int NB)
{
    __shared__ int wsum[4];
    int b = blockIdx.x;
    int tid = threadIdx.x;
    int chunk = (NBLK + 255) >> 8;
    int k0 = tid * chunk;
    int s = 0;
    for (int j = 0; j < chunk; ++j) {
        int k = k0 + j;
        if (k < NBLK) s += gmat[(size_t)k * NB + b];
    }
    int lane = tid & 63, w = tid >> 6;
    int sc = s;
#pragma unroll
    for (int off = 1; off < 64; off <<= 1) {
        int t = __shfl_up(sc, off, 64);
        if (lane >= off) sc += t;
    }
    if (lane == 63) wsum[w] = sc;
    __syncthreads();
    if (tid == 0) { int a = 0; for (int i = 0; i < 4; ++i) { int t = wsum[i]; wsum[i] = a; a += t; } }
    __syncthreads();
    int run = sc - s + wsum[w];
    for (int j = 0; j < chunk; ++j) {
        int k = k0 + j;
        if (k < NBLK) {
            int gv = gmat[(size_t)k * NB + b];
            pbaseRel[(size_t)k * NB + b] = run;
            run += gv;
        }
    }
    if (tid == 255) total[b] = run;
}

// scan bucket totals -> cptr (single block, chunked over NB)
__global__ __launch_bounds__(512) void ptot(const int* __restrict__ total, int* __restrict__ cptr,
                                            int* __restrict__ row_ptr, int NB, int n, int E)
{
    __shared__ int wsum[8];
    int tid = threadIdx.x;
    int chunk = (NB + 511) >> 9;
    int k0 = tid * chunk;
    int s = 0;
    for (int j = 0; j < chunk; ++j) {
        int k = k0 + j;
        if (k < NB) s += total[k];
    }
    int lane = tid & 63, w = tid >> 6;
    int sc = s;
#pragma unroll
    for (int off = 1; off < 64; off <<= 1) {
        int t = __shfl_up(sc, off, 64);
        if (lane >= off) sc += t;
    }
    if (lane == 63) wsum[w] = sc;
    __syncthreads();
    if (tid == 0) { int a = 0; for (int i = 0; i < 8; ++i) { int t = wsum[i]; wsum[i] = a; a += t; } }
    __syncthreads();
    int run = sc - s + wsum[w];
    for (int j = 0; j < chunk; ++j) {
        int k = k0 + j;
        if (k < NB) { cptr[k] = run; run += total[k]; }
    }
    if (tid == 0) { cptr[NB] = E; row_ptr[n] = E; }
}

// pass 1b: LDS write-combining at coarse granularity; histogram read from gmat.
__global__ __launch_bounds__(256) void p1bW(const int* __restrict__ src, const int* __restrict__ dst,
    const int* __restrict__ gmat, const int* __restrict__ cptr, const int* __restrict__ pbaseRel,
    unsigned* __restrict__ stage, int E, int NB)
{
    __shared__ int lbase[MAXNB], bbase[MAXNB], ccur[MAXNB];
    __shared__ unsigned bufp[CHUNK];
    __shared__ unsigned short bufb[CHUNK];
    __shared__ int wsum[4];
    int tid = threadIdx.x;
    const int* grow = gmat + (size_t)blockIdx.x * NB;
    const int* prow = pbaseRel + (size_t)blockIdx.x * NB;

    int base = blockIdx.x * CHUNK;
    int end = base + CHUNK; if (end > E) end = E;
    int cnt = end - base;

    // chunked exclusive scan of this block's histogram row
    int chunkb = (NB + 255) >> 8;
    int b0 = tid * chunkb;
    int s = 0;
    for (int j = 0; j < chunkb; ++j) {
        int b = b0 + j;
        if (b < NB) s += grow[b];
    }
    int lane = tid & 63, w = tid >> 6;
    int sc = s;
#pragma unroll
    for (int off = 1; off < 64; off <<= 1) {
        int t = __shfl_up(sc, off, 64);
        if (lane >= off) sc += t;
    }
    if (lane == 63) wsum[w] = sc;
    __syncthreads();
    if (tid == 0) { int a = 0; for (int i = 0; i < 4; ++i) { int t = wsum[i]; wsum[i] = a; a += t; } }
    __syncthreads();
    int run = sc - s + wsum[w];
    for (int j = 0; j < chunkb; ++j) {
        int b = b0 + j;
        if (b < NB) {
            lbase[b] = run;
            run += grow[b];
            bbase[b] = cptr[b] + prow[b];
            ccur[b] = 0;
        }
    }
    __syncthreads();

    // LDS scatter (random LDS, cheap); pack carries 9 fine bits
    for (int i = base + tid; i < end; i += 256) {
        int d = dst[i];
        int b = d >> CSHIFT;
        int off = atomicAdd(&ccur[b], 1);
        int pos = lbase[b] + off;
        bufp[pos] = ((unsigned)(d & (BUCKN - 1)) << 17) | (unsigned)src[i];
        bufb[pos] = (unsigned short)b;
    }
    __syncthreads();

    // flush: consecutive local positions within a bucket -> consecutive global (runs of ~21)
    for (int i = tid; i < cnt; i += 256) {
        int b = bufb[i];
        stage[bbase[b] + (i - lbase[b])] = bufp[i];
    }
}

// pass 2 (split): 4 sub-blocks per coarse bucket; each sorts+emits one 128-node quarter.
__global__ __launch_bounds__(512) void p2s(const unsigned* __restrict__ stage,
    const int* __restrict__ cptr, int* __restrict__ colsrc, int* __restrict__ row_ptr, int n)
{
    int b = blockIdx.x >> 2;          // coarse bucket
    int j = blockIdx.x & 3;           // quarter
    int nbase = (b << CSHIFT) + j * 128;
    __shared__ int h[BUCKN], cc[128];
    __shared__ int wsum[8];
    __shared__ int buf[FBUF];
    int tid = threadIdx.x;
    h[tid] = 0;
    if (tid < 128) cc[tid] = 0;
    __syncthreads();
    int s0 = cptr[b], s1 = cptr[b + 1];
    int span = s1 - s0;

    // full 512-bin histogram of the coarse span
    for (int i = s0 + tid; i < s1; i += 512)
        atomicAdd(&h[stage[i] >> 17], 1);
    __syncthreads();

    // exclusive scan of 512 bins (each thread owns one)
    int v = h[tid];
    int lane = tid & 63, w = tid >> 6;
    int sc = v;
#pragma unroll
    for (int off = 1; off < 64; off <<= 1) {
        int t = __shfl_up(sc, off, 64);
        if (lane >= off) sc += t;
    }
    if (lane == 63) wsum[w] = sc;
    __syncthreads();
    if (tid == 0) { int a = 0; for (int i = 0; i < 8; ++i) { int t = wsum[i]; wsum[i] = a; a += t; } }
    __syncthreads();
    int excl = sc - v + wsum[w];
    h[tid] = excl;                    // h now holds within-bucket exclusive offsets
    __syncthreads();

    int q0 = j * 128;
    int substart = h[q0];
    int subend = (j == 3) ? span : h[q0 + 128];
    int subspan = subend - substart;

    if (tid < 128) {
        int node = nbase + tid;
        if (node < n) row_ptr[node] = s0 + h[q0 + tid];
    }
    __syncthreads();

    if (subspan <= FBUF) {
        // scatter my quarter into LDS, flush coalesced
        for (int i = s0 + tid; i < s1; i += 512) {
            unsigned p = stage[i];
            int f = p >> 17;
            if ((f >> 7) == j) {
                int off = atomicAdd(&cc[f & 127], 1);
                buf[h[f] - substart + off] = (int)(p & 0x1FFFFu);
            }
        }
        __syncthreads();
        int gbase = s0 + substart;
        for (int i = tid; i < subspan; i += 512)
            colsrc[gbase + i] = buf[i];
    } else {
        // pathological quarter: direct scatter
        for (int i = s0 + tid; i < s1; i += 512) {
            unsigned p = stage[i];
            int f = p >> 17;
            if ((f >> 7) == j) {
                int off = atomicAdd(&cc[f & 127], 1);
                colsrc[s0 + h[f] + off] = (int)(p & 0x1FFFFu);
            }
        }
    }
}

// ============================ gathers (packed 32B rows, 16 lanes/node, 4 nodes/wave) ============================

// Layer 1 gather -> h' packed (16B fp16 h' | fp32 as2 | pad); ad2 separate.
// as2/ad2 via precomputed W2@a2s / W2@a2d (aggregation commutes with W2).
__global__ __launch_bounds__(256) void k_gather8f(const int* __restrict__ row_ptr,
    const int* __restrict__ colsrc, const float4* __restrict__ featpk, const float* __restrict__ ad,
    const float* __restrict__ b1, const float* __restrict__ W2,
    const float* __restrict__ a2s, const float* __restrict__ a2d,
    float4* __restrict__ outpk, float* __restrict__ ad2, int n)
{
    __shared__ float w2as[8], w2ad[8], b1v[8];
    if (threadIdx.x < 8) {
        float s = 0.f, d = 0.f;
#pragma unroll
        for (int c = 0; c < 16; ++c) {
            float wv = W2[threadIdx.x * 16 + c];
            s += wv * a2s[c];
            d += wv * a2d[c];
        }
        w2as[threadIdx.x] = s;
        w2ad[threadIdx.x] = d;
        b1v[threadIdx.x] = b1[threadIdx.x];
    }
    __syncthreads();

    int wid  = (blockIdx.x * 256 + threadIdx.x) >> 6;
    int lane = threadIdx.x & 63;
    int l16  = lane & 15;
    int node = wid * 4 + (lane >> 4);
    bool active = node < n;

    int start = 0, end = 0;
    float adn = 0.f;
    if (active) { start = row_ptr[node]; end = row_ptr[node + 1]; adn = ad[node]; }

    float wsum = 0.f, acc[8];
#pragma unroll
    for (int k = 0; k < 8; ++k) acc[k] = 0.f;

    for (int i = start + l16; i < end; i += 16) {
        int s = colsrc[i];
        union { float4 fv; __half2 h[4]; } u;
        u.fv = featpk[2 * (size_t)s];            // 16B fp16 h row
        float4 meta = featpk[2 * (size_t)s + 1]; // alpha_s in .x (same 32B line)
        float t = meta.x + adn;
        float w = __expf(t > 0.f ? t : NEG * t); // max-shift skipped: |t| small, exact ratio
        wsum += w;
#pragma unroll
        for (int q = 0; q < 4; ++q) {
            float2 hv = __half22float2(u.h[q]);
            acc[2 * q + 0] += w * hv.x;
            acc[2 * q + 1] += w * hv.y;
        }
    }
#pragma unroll
    for (int off = 8; off; off >>= 1) {
        wsum += __shfl_xor(wsum, off, 64);
#pragma unroll
        for (int k = 0; k < 8; ++k) acc[k] += __shfl_xor(acc[k], off, 64);
    }
    if (!active || l16 != 0) return;

    float inv = wsum > 0.f ? 1.f / wsum : 0.f;
    float h[8], s2 = 0.f, d2 = 0.f;
    union { float4 f; __half2 hh[4]; } u;
#pragma unroll
    for (int k = 0; k < 8; ++k) {
        float v = acc[k] * inv + b1v[k];
        h[k] = v > 0.f ? v : 0.f;
        s2 += h[k] * w2as[k];
        d2 += h[k] * w2ad[k];
    }
#pragma unroll
    for (int q = 0; q < 4; ++q) u.hh[q] = __floats2half2_rn(h[2 * q], h[2 * q + 1]);
    outpk[2 * (size_t)node]     = u.f;
    outpk[2 * (size_t)node + 1] = make_float4(s2, 0.f, 0.f, 0.f);
    ad2[node] = d2;
}

// Layer 2 gather on packed h' (8-dim), W2 per-node after normalization, fused log_softmax.
__global__ __launch_bounds__(256) void k_gather16(const int* __restrict__ row_ptr,
    const int* __restrict__ colsrc, const float4* __restrict__ featpk, const float* __restrict__ ad,
    const float* __restrict__ W2, const float* __restrict__ bias, float* __restrict__ outp, int n)
{
    __shared__ float w2s[128], bv[16];
    if (threadIdx.x < 128) w2s[threadIdx.x] = W2[threadIdx.x];
    else if (threadIdx.x < 144) bv[threadIdx.x - 128] = bias[threadIdx.x - 128];
    __syncthreads();

    int wid  = (blockIdx.x * 256 + threadIdx.x) >> 6;
    int lane = threadIdx.x & 63;
    int l16  = lane & 15;
    int node = wid * 4 + (lane >> 4);
    bool active = node < n;

    int start = 0, end = 0;
    float adn = 0.f;
    if (active) { start = row_ptr[node]; end = row_ptr[node + 1]; adn = ad[node]; }

    float wsum = 0.f, acc[8];
#pragma unroll
    for (int k = 0; k < 8; ++k) acc[k] = 0.f;

    for (int i = start + l16; i < end; i += 16) {
        int s = colsrc[i];
        union { float4 fv; __half2 h[4]; } u;
        u.fv = featpk[2 * (size_t)s];
        float4 meta = featpk[2 * (size_t)s + 1];
        float t = meta.x + adn;
        float w = __expf(t > 0.f ? t : NEG * t);
        wsum += w;
#pragma unroll
        for (int q = 0; q < 4; ++q) {
            float2 hv = __half22float2(u.h[q]);
            acc[2 * q + 0] += w * hv.x;
            acc[2 * q + 1] += w * hv.y;
        }
    }
#pragma unroll
    for (int off = 8; off; off >>= 1) {
        wsum += __shfl_xor(wsum, off, 64);
#pragma unroll
        for (int k = 0; k < 8; ++k) acc[k] += __shfl_xor(acc[k], off, 64);
    }
    if (!active) return;

    float inv = wsum > 0.f ? 1.f / wsum : 0.f;
    float o = bv[l16];
#pragma unroll
    for (int k = 0; k < 8; ++k) o += (acc[k] * inv) * w2s[k * 16 + l16];
    float m = o;
#pragma unroll
    for (int off = 8; off; off >>= 1) m = fmaxf(m, __shfl_xor(m, off, 64));
    float se = __expf(o - m);
#pragma unroll
    for (int off = 8; off; off >>= 1) se += __shfl_xor(se, off, 64);
    float l = m + __logf(se);
    outp[(size_t)node * 16 + l16] = o - l;
}

// ============================ fallback: pure atomic path (fp32) ============================

__global__ __launch_bounds__(256) void k1_nodeF(const float* __restrict__ x,
    const float* __restrict__ W1, const float* __restrict__ a1s, const float* __restrict__ a1d,
    float* __restrict__ h1, float* __restrict__ as1, float* __restrict__ ad1, int n)
{
    __shared__ float wt[8 * 128];
    __shared__ float av[16];
    for (int i = threadIdx.x; i < 1024; i += 256) {
        int r = i >> 3, k = i & 7;
        wt[k * 128 + r] = W1[i];
    }
    if (threadIdx.x < 8)        av[threadIdx.x] = a1s[threadIdx.x];
    else if (threadIdx.x < 16)  av[threadIdx.x] = a1d[threadIdx.x - 8];
    __syncthreads();

    int lane = threadIdx.x & 31;
    int node = blockIdx.x * 8 + (threadIdx.x >> 5);
    if (node >= n) return;

    float4 xv = ((const float4*)(x + (size_t)node * 128))[lane];
    float p[8];
#pragma unroll
    for (int k = 0; k < 8; ++k) {
        float4 wv = ((const float4*)(wt + k * 128))[lane];
        p[k] = xv.x * wv.x + xv.y * wv.y + xv.z * wv.z + xv.w * wv.w;
    }
#pragma unroll
    for (int off = 16; off; off >>= 1)
#pragma unroll
        for (int k = 0; k < 8; ++k) p[k] += __shfl_down(p[k], off, 32);

    if (lane == 0) {
        float s = 0.f, d = 0.f;
#pragma unroll
        for (int k = 0; k < 8; ++k) {
            h1[(size_t)node * 8 + k] = p[k];
            s += p[k] * av[k];
            d += p[k] * av[8 + k];
        }
        as1[node] = s;
        ad1[node] = d;
    }
}

template <int F>
__global__ __launch_bounds__(256) void k_edge(const int* __restrict__ src, const int* __restrict__ dst,
    const float* __restrict__ as, const float* __restrict__ ad, const float* __restrict__ feat,
    float* __restrict__ denom, float* __restrict__ acc, int E)
{
    int e = blockIdx.x * 256 + threadIdx.x;
    if (e >= E) return;
    int s = src[e], d = dst[e];
    float t = as[s] + ad[d];
    float w = __expf(t > 0.f ? t : NEG * t);
    atomicAdd(denom + d, w);
    const float* fs = feat + (size_t)s * F;
    float* ac = acc + (size_t)d * F;
#pragma unroll
    for (int k = 0; k < F; ++k) atomicAdd(ac + k, w * fs[k]);
}

__global__ __launch_bounds__(256) void k3_node(const float* __restrict__ denom1,
    const float* __restrict__ acc1, const float* __restrict__ b1,
    const float* __restrict__ W2, const float* __restrict__ a2s, const float* __restrict__ a2d,
    float* __restrict__ g, float* __restrict__ as2, float* __restrict__ ad2, int n)
{
    __shared__ float w2[128];
    __shared__ float aa[32];
    __shared__ float bb[8];
    if (threadIdx.x < 128) w2[threadIdx.x] = W2[threadIdx.x];
    if (threadIdx.x >= 128 && threadIdx.x < 144) aa[threadIdx.x - 128] = a2s[threadIdx.x - 128];
    if (threadIdx.x >= 144 && threadIdx.x < 160) aa[16 + threadIdx.x - 144] = a2d[threadIdx.x - 144];
    if (threadIdx.x >= 160 && threadIdx.x < 168) bb[threadIdx.x - 160] = b1[threadIdx.x - 160];
    __syncthreads();

    int node = blockIdx.x * 256 + threadIdx.x;
    if (node >= n) return;
    float dn = denom1[node];
    float inv = dn > 0.f ? 1.f / dn : 0.f;
    float h[8];
#pragma unroll
    for (int k = 0; k < 8; ++k) {
        float v = acc1[(size_t)node * 8 + k] * inv + bb[k];
        h[k] = v > 0.f ? v : 0.f;
    }
    float s = 0.f, dd = 0.f;
#pragma unroll
    for (int c = 0; c < 16; ++c) {
        float gv = 0.f;
#pragma unroll
        for (int k = 0; k < 8; ++k) gv += h[k] * w2[k * 16 + c];
        g[(size_t)node * 16 + c] = gv;
        s += gv * aa[c];
        dd += gv * aa[16 + c];
    }
    as2[node] = s;
    ad2[node] = dd;
}

__global__ __launch_bounds__(256) void k5_final(const float* __restrict__ denom2,
    const float* __restrict__ acc2, const float* __restrict__ b2, float* __restrict__ out, int n)
{
    __shared__ float bb[16];
    if (threadIdx.x < 16) bb[threadIdx.x] = b2[threadIdx.x];
    __syncthreads();

    int node = blockIdx.x * 256 + threadIdx.x;
    if (node >= n) return;
    float dn = denom2[node];
    float inv = dn > 0.f ? 1.f / dn : 0.f;
    float o[16];
    float m = -1e30f;
#pragma unroll
    for (int c = 0; c < 16; ++c) {
        o[c] = acc2[(size_t)node * 16 + c] * inv + bb[c];
        m = fmaxf(m, o[c]);
    }
    float se = 0.f;
#pragma unroll
    for (int c = 0; c < 16; ++c) {
        o[c] -= m;
        se += __expf(o[c]);
    }
    float l = __logf(se);
#pragma unroll
    for (int c = 0; c < 16; ++c) out[(size_t)node * 16 + c] = o[c] - l;
}

// ============================ launch ============================

static inline char* align256(char* p) {
    return (char*)(((uintptr_t)p + 255) & ~(uintptr_t)255);
}

extern "C" void kernel_launch(void* const* d_in, const int* in_sizes, int n_in,
                              void* d_out, int out_size, void* d_ws, size_t ws_size,
                              hipStream_t stream)
{
    const float* x    = (const float*)d_in[0];
    const int*   eidx = (const int*)d_in[1];
    const float* W1   = (const float*)d_in[2];
    const float* a1s  = (const float*)d_in[3];
    const float* a1d  = (const float*)d_in[4];
    const float* b1   = (const float*)d_in[5];
    const float* W2   = (const float*)d_in[6];
    const float* a2s  = (const float*)d_in[7];
    const float* a2d  = (const float*)d_in[8];
    const float* b2   = (const float*)d_in[9];
    float* out = (float*)d_out;

    const int n = in_sizes[0] / 128;
    const int E = in_sizes[1] / 2;
    const int* src = eidx;
    const int* dst = eidx + E;
    const int NB = (n + BUCKN - 1) >> CSHIFT;
    const int NBLK = (E + CHUNK - 1) / CHUNK;

    // ---- tier-0: bucket-sort CSR (gmat/pbaseRel aliased into colsrc) + packed fp16 gathers ----
    {
        char* p = (char*)d_ws;
        char* p0 = p;
        unsigned* stage = (unsigned*)p;  p = align256(p + (size_t)E * 4);
        int* colsrc  = (int*)p;          p = align256(p + (size_t)E * 4);
        int* total   = (int*)p;          p = align256(p + (size_t)NB * 4);
        int* cptr    = (int*)p;          p = align256(p + (size_t)(NB + 1) * 4);
        int* row_ptr = (int*)p;          p = align256(p + (size_t)(n + 1) * 4);
        float4* h1pk  = (float4*)p;      p = align256(p + (size_t)n * 32);
        float4* h1ppk = (float4*)p;      p = align256(p + (size_t)n * 32);
        float* ad1   = (float*)p;        p = align256(p + (size_t)n * 4);
        float* ad2   = (float*)p;        p = align256(p + (size_t)n * 4);
        size_t needed = (size_t)(p - p0);

        int* gmat     = colsrc;                       // alias (dead before p2s)
        int* pbaseRel = (int*)align256((char*)(colsrc + (size_t)NBLK * NB));

        bool alias_ok = ((size_t)2 * NBLK * NB + 64) <= (size_t)E;

        if (n <= 131072 && NB <= MAXNB && alias_ok && ws_size >= needed) {
            k1_node<<<(n + 7) / 8, 256, 0, stream>>>(x, W1, a1s, a1d, h1pk, ad1, n);

            p1a<<<NBLK, 256, 0, stream>>>(dst, gmat, E, NB);
            pcol<<<NB, 256, 0, stream>>>(gmat, pbaseRel, total, NBLK, NB);
            ptot<<<1, 512, 0, stream>>>(total, cptr, row_ptr, NB, n, E);
            p1bW<<<NBLK, 256, 0, stream>>>(src, dst, gmat, cptr, pbaseRel, stage, E, NB);
            p2s<<<NB * 4, 512, 0, stream>>>(stage, cptr, colsrc, row_ptr, n);

            // 16 lanes per node, 4 nodes per wave
            const int gblocks = ((size_t)n * 16 + 255) / 256;
            k_gather8f<<<gblocks, 256, 0, stream>>>(row_ptr, colsrc, h1pk, ad1,
                                                    b1, W2, a2s, a2d, h1ppk, ad2, n);
            k_gather16<<<gblocks, 256, 0, stream>>>(row_ptr, colsrc, h1ppk, ad2, W2, b2, out, n);
            return;
        }
    }

    // ---- fallback: pure atomic path (fp32) ----
    {
        float* ws     = (float*)d_ws;
        float* denom1 = ws;
        float* acc1   = ws + (size_t)n;
        float* denom2 = ws + (size_t)9 * n;
        float* acc2   = ws + (size_t)10 * n;
        float* h1     = ws + (size_t)26 * n;
        float* as1    = ws + (size_t)34 * n;
        float* ad1    = ws + (size_t)35 * n;
        float* g      = ws + (size_t)36 * n;
        float* as2    = ws + (size_t)52 * n;
        float* ad2    = ws + (size_t)53 * n;

        hipMemsetAsync(ws, 0, (size_t)26 * n * sizeof(float), stream);
        k1_nodeF<<<(n + 7) / 8, 256, 0, stream>>>(x, W1, a1s, a1d, h1, as1, ad1, n);
        k_edge<8><<<(E + 255) / 256, 256, 0, stream>>>(src, dst, as1, ad1, h1, denom1, acc1, E);
        k3_node<<<(n + 255) / 256, 256, 0, stream>>>(denom1, acc1, b1, W2, a2s, a2d, g, as2, ad2, n);
        k_edge<16><<<(E + 255) / 256, 256, 0, stream>>>(src, dst, as2, ad2, g, denom2, acc2, E);
        k5_final<<<(n + 255) / 256, 256, 0, stream>>>(denom2, acc2, b2, out, n);
    }
}

// Round 19
// 189.519 us; speedup vs baseline: 1.1414x; 1.1414x over previous
//
#include <hip/hip_runtime.h>
#include <hip/hip_fp16.h>
#include <math.h>
#include <stdint.h>

#define NEG 0.2f
#define CSHIFT 9
#define BUCKN (1 << CSHIFT)     // 512 nodes per coarse bucket
#define MAXNB 256               // NB <= 256 for n <= 131072 (CSHIFT=9)
#define CHUNK 4096
#define FBUF2 34816             // full-span staged colsrc (mean 32.6K @ n=100k/E=6.4M; 12-sigma headroom)

// ============================ node transform (packed 32B rows: 8 fp16 h | fp32 alpha_s | pad) ============================

__global__ __launch_bounds__(256) void k1_node(const float* __restrict__ x,
    const float* __restrict__ W1, const float* __restrict__ a1s, const float* __restrict__ a1d,
    float4* __restrict__ h1pk, float* __restrict__ ad1, int n)
{
    __shared__ float wt[8 * 128];
    __shared__ float av[16];
    for (int i = threadIdx.x; i < 1024; i += 256) {
        int r = i >> 3, k = i & 7;
        wt[k * 128 + r] = W1[i];
    }
    if (threadIdx.x < 8)        av[threadIdx.x] = a1s[threadIdx.x];
    else if (threadIdx.x < 16)  av[threadIdx.x] = a1d[threadIdx.x - 8];
    __syncthreads();

    int lane = threadIdx.x & 31;
    int node = blockIdx.x * 8 + (threadIdx.x >> 5);
    if (node >= n) return;

    float4 xv = ((const float4*)(x + (size_t)node * 128))[lane];
    float p[8];
#pragma unroll
    for (int k = 0; k < 8; ++k) {
        float4 wv = ((const float4*)(wt + k * 128))[lane];
        p[k] = xv.x * wv.x + xv.y * wv.y + xv.z * wv.z + xv.w * wv.w;
    }
#pragma unroll
    for (int off = 16; off; off >>= 1)
#pragma unroll
        for (int k = 0; k < 8; ++k) p[k] += __shfl_down(p[k], off, 32);

    if (lane == 0) {
        float s = 0.f, d = 0.f;
        union { float4 f; __half2 h[4]; } u;
#pragma unroll
        for (int k = 0; k < 8; ++k) {
            s += p[k] * av[k];
            d += p[k] * av[8 + k];
        }
#pragma unroll
        for (int q = 0; q < 4; ++q) u.h[q] = __floats2half2_rn(p[2 * q], p[2 * q + 1]);
        h1pk[2 * (size_t)node]     = u.f;                        // 16B fp16 h row
        h1pk[2 * (size_t)node + 1] = make_float4(s, 0.f, 0.f, 0.f);  // alpha_s
        ad1[node] = d;
    }
}

// ============================ bucket-sort CSR build (all-parallel, atomic-free) ============================

__global__ __launch_bounds__(256) void p1a(const int* __restrict__ dst, int* __restrict__ gmat,
                                           int E, int NB)
{
    __shared__ int h[MAXNB];
    for (int i = threadIdx.x; i < NB; i += 256) h[i] = 0;
    __syncthreads();
    int base = blockIdx.x * CHUNK;
    int end = base + CHUNK; if (end > E) end = E;
    for (int i = base + threadIdx.x; i < end; i += 256)
        atomicAdd(&h[dst[i] >> CSHIFT], 1);
    __syncthreads();
    int* row = gmat + (size_t)blockIdx.x * NB;
    for (int i = threadIdx.x; i < NB; i += 256) row[i] = h[i];
}

__global__ __launch_bounds__(256) void pcol(const int* __restrict__ gmat, int* __restrict__ pbaseRel,
    int* __restrict__ total, int NBLK, int NB)
{
    __shared__ int wsum[4];
    int b = blockIdx.x;
    int tid = threadIdx.x;
    int chunk = (NBLK + 255) >> 8;
    int k0 = tid * chunk;
    int s = 0;
    for (int j = 0; j < chunk; ++j) {
        int k = k0 + j;
        if (k < NBLK) s += gmat[(size_t)k * NB + b];
    }
    int lane = tid & 63, w = tid >> 6;
    int sc = s;
#pragma unroll
    for (int off = 1; off < 64; off <<= 1) {
        int t = __shfl_up(sc, off, 64);
        if (lane >= off) sc += t;
    }
    if (lane == 63) wsum[w] = sc;
    __syncthreads();
    if (tid == 0) { int a = 0; for (int i = 0; i < 4; ++i) { int t = wsum[i]; wsum[i] = a; a += t; } }
    __syncthreads();
    int run = sc - s + wsum[w];
    for (int j = 0; j < chunk; ++j) {
        int k = k0 + j;
        if (k < NBLK) {
            int gv = gmat[(size_t)k * NB + b];
            pbaseRel[(size_t)k * NB + b] = run;
            run += gv;
        }
    }
    if (tid == 255) total[b] = run;
}

// scan bucket totals -> cptr (single block, chunked over NB)
__global__ __launch_bounds__(512) void ptot(const int* __restrict__ total, int* __restrict__ cptr,
                                            int* __restrict__ row_ptr, int NB, int n, int E)
{
    __shared__ int wsum[8];
    int tid = threadIdx.x;
    int chunk = (NB + 511) >> 9;
    int k0 = tid * chunk;
    int s = 0;
    for (int j = 0; j < chunk; ++j) {
        int k = k0 + j;
        if (k < NB) s += total[k];
    }
    int lane = tid & 63, w = tid >> 6;
    int sc = s;
#pragma unroll
    for (int off = 1; off < 64; off <<= 1) {
        int t = __shfl_up(sc, off, 64);
        if (lane >= off) sc += t;
    }
    if (lane == 63) wsum[w] = sc;
    __syncthreads();
    if (tid == 0) { int a = 0; for (int i = 0; i < 8; ++i) { int t = wsum[i]; wsum[i] = a; a += t; } }
    __syncthreads();
    int run = sc - s + wsum[w];
    for (int j = 0; j < chunk; ++j) {
        int k = k0 + j;
        if (k < NB) { cptr[k] = run; run += total[k]; }
    }
    if (tid == 0) { cptr[NB] = E; row_ptr[n] = E; }
}

// pass 1b: LDS write-combining at coarse granularity; histogram read from gmat.
__global__ __launch_bounds__(256) void p1bW(const int* __restrict__ src, const int* __restrict__ dst,
    const int* __restrict__ gmat, const int* __restrict__ cptr, const int* __restrict__ pbaseRel,
    unsigned* __restrict__ stage, int E, int NB)
{
    __shared__ int lbase[MAXNB], bbase[MAXNB], ccur[MAXNB];
    __shared__ unsigned bufp[CHUNK];
    __shared__ unsigned short bufb[CHUNK];
    __shared__ int wsum[4];
    int tid = threadIdx.x;
    const int* grow = gmat + (size_t)blockIdx.x * NB;
    const int* prow = pbaseRel + (size_t)blockIdx.x * NB;

    int base = blockIdx.x * CHUNK;
    int end = base + CHUNK; if (end > E) end = E;
    int cnt = end - base;

    // chunked exclusive scan of this block's histogram row
    int chunkb = (NB + 255) >> 8;
    int b0 = tid * chunkb;
    int s = 0;
    for (int j = 0; j < chunkb; ++j) {
        int b = b0 + j;
        if (b < NB) s += grow[b];
    }
    int lane = tid & 63, w = tid >> 6;
    int sc = s;
#pragma unroll
    for (int off = 1; off < 64; off <<= 1) {
        int t = __shfl_up(sc, off, 64);
        if (lane >= off) sc += t;
    }
    if (lane == 63) wsum[w] = sc;
    __syncthreads();
    if (tid == 0) { int a = 0; for (int i = 0; i < 4; ++i) { int t = wsum[i]; wsum[i] = a; a += t; } }
    __syncthreads();
    int run = sc - s + wsum[w];
    for (int j = 0; j < chunkb; ++j) {
        int b = b0 + j;
        if (b < NB) {
            lbase[b] = run;
            run += grow[b];
            bbase[b] = cptr[b] + prow[b];
            ccur[b] = 0;
        }
    }
    __syncthreads();

    // LDS scatter (random LDS, cheap); pack carries 9 fine bits
    for (int i = base + tid; i < end; i += 256) {
        int d = dst[i];
        int b = d >> CSHIFT;
        int off = atomicAdd(&ccur[b], 1);
        int pos = lbase[b] + off;
        bufp[pos] = ((unsigned)(d & (BUCKN - 1)) << 17) | (unsigned)src[i];
        bufb[pos] = (unsigned short)b;
    }
    __syncthreads();

    // flush: consecutive local positions within a bucket -> consecutive global (runs of ~21)
    for (int i = tid; i < cnt; i += 256) {
        int b = bufb[i];
        stage[bbase[b] + (i - lbase[b])] = bufp[i];
    }
}

// pass 2 (full-span): one block per coarse bucket; histogram + scan + LDS-staged coalesced emit.
__global__ __launch_bounds__(1024) void p2f(const unsigned* __restrict__ stage,
    const int* __restrict__ cptr, int* __restrict__ colsrc, int* __restrict__ row_ptr, int n)
{
    int b = blockIdx.x;
    int nbase = b << CSHIFT;
    int NN = n - nbase; if (NN > BUCKN) NN = BUCKN;
    __shared__ int h[BUCKN], cc[BUCKN];  // 4 KB
    __shared__ int wsum[8];
    __shared__ int buf[FBUF2];           // 136 KB staged colsrc image
    int tid = threadIdx.x;
    if (tid < BUCKN) { h[tid] = 0; cc[tid] = 0; }
    __syncthreads();
    int s0 = cptr[b], s1 = cptr[b + 1];
    int span = s1 - s0;

    // 1st pass: 512-bin histogram (streaming read)
    for (int i = s0 + tid; i < s1; i += 1024)
        atomicAdd(&h[stage[i] >> 17], 1);
    __syncthreads();

    // exclusive scan of 512 bins (first 8 waves own one bin each)
    int v = (tid < BUCKN) ? h[tid] : 0;
    int lane = tid & 63, w = tid >> 6;
    int sc = v;
#pragma unroll
    for (int off = 1; off < 64; off <<= 1) {
        int t = __shfl_up(sc, off, 64);
        if (lane >= off) sc += t;
    }
    if (tid < BUCKN && lane == 63) wsum[w] = sc;
    __syncthreads();
    if (tid == 0) { int a = 0; for (int i = 0; i < 8; ++i) { int t = wsum[i]; wsum[i] = a; a += t; } }
    __syncthreads();
    if (tid < BUCKN) {
        int excl = sc - v + wsum[w];
        h[tid] = excl;                    // within-bucket exclusive offset
        if (tid < NN) row_ptr[nbase + tid] = s0 + excl;
    }
    __syncthreads();

    if (span <= FBUF2) {
        // 2nd pass: scatter into LDS (stage re-read is L2-resident), flush coalesced
        for (int i = s0 + tid; i < s1; i += 1024) {
            unsigned p = stage[i];
            int f = p >> 17;
            int off = atomicAdd(&cc[f], 1);
            buf[h[f] + off] = (int)(p & 0x1FFFFu);
        }
        __syncthreads();
        for (int i = tid; i < span; i += 1024)
            colsrc[s0 + i] = buf[i];
    } else {
        // pathological bucket: direct scatter (correct for any distribution)
        for (int i = s0 + tid; i < s1; i += 1024) {
            unsigned p = stage[i];
            int f = p >> 17;
            int off = atomicAdd(&cc[f], 1);
            colsrc[s0 + h[f] + off] = (int)(p & 0x1FFFFu);
        }
    }
}

// ============================ gathers (packed 32B rows, 16 lanes/node, 4 nodes/wave) ============================

// Layer 1 gather -> h' packed (16B fp16 h' | fp32 as2 | pad); ad2 separate.
// as2/ad2 via precomputed W2@a2s / W2@a2d (aggregation commutes with W2).
__global__ __launch_bounds__(256) void k_gather8f(const int* __restrict__ row_ptr,
    const int* __restrict__ colsrc, const float4* __restrict__ featpk, const float* __restrict__ ad,
    const float* __restrict__ b1, const float* __restrict__ W2,
    const float* __restrict__ a2s, const float* __restrict__ a2d,
    float4* __restrict__ outpk, float* __restrict__ ad2, int n)
{
    __shared__ float w2as[8], w2ad[8], b1v[8];
    if (threadIdx.x < 8) {
        float s = 0.f, d = 0.f;
#pragma unroll
        for (int c = 0; c < 16; ++c) {
            float wv = W2[threadIdx.x * 16 + c];
            s += wv * a2s[c];
            d += wv * a2d[c];
        }
        w2as[threadIdx.x] = s;
        w2ad[threadIdx.x] = d;
        b1v[threadIdx.x] = b1[threadIdx.x];
    }
    __syncthreads();

    int wid  = (blockIdx.x * 256 + threadIdx.x) >> 6;
    int lane = threadIdx.x & 63;
    int l16  = lane & 15;
    int node = wid * 4 + (lane >> 4);
    bool active = node < n;

    int start = 0, end = 0;
    float adn = 0.f;
    if (active) { start = row_ptr[node]; end = row_ptr[node + 1]; adn = ad[node]; }

    float wsum = 0.f, acc[8];
#pragma unroll
    for (int k = 0; k < 8; ++k) acc[k] = 0.f;

    for (int i = start + l16; i < end; i += 16) {
        int s = colsrc[i];
        union { float4 fv; __half2 h[4]; } u;
        u.fv = featpk[2 * (size_t)s];            // 16B fp16 h row
        float4 meta = featpk[2 * (size_t)s + 1]; // alpha_s in .x (same 32B line)
        float t = meta.x + adn;
        float w = __expf(t > 0.f ? t : NEG * t); // max-shift skipped: |t| small, exact ratio
        wsum += w;
#pragma unroll
        for (int q = 0; q < 4; ++q) {
            float2 hv = __half22float2(u.h[q]);
            acc[2 * q + 0] += w * hv.x;
            acc[2 * q + 1] += w * hv.y;
        }
    }
#pragma unroll
    for (int off = 8; off; off >>= 1) {
        wsum += __shfl_xor(wsum, off, 64);
#pragma unroll
        for (int k = 0; k < 8; ++k) acc[k] += __shfl_xor(acc[k], off, 64);
    }
    if (!active || l16 != 0) return;

    float inv = wsum > 0.f ? 1.f / wsum : 0.f;
    float h[8], s2 = 0.f, d2 = 0.f;
    union { float4 f; __half2 hh[4]; } u;
#pragma unroll
    for (int k = 0; k < 8; ++k) {
        float v = acc[k] * inv + b1v[k];
        h[k] = v > 0.f ? v : 0.f;
        s2 += h[k] * w2as[k];
        d2 += h[k] * w2ad[k];
    }
#pragma unroll
    for (int q = 0; q < 4; ++q) u.hh[q] = __floats2half2_rn(h[2 * q], h[2 * q + 1]);
    outpk[2 * (size_t)node]     = u.f;
    outpk[2 * (size_t)node + 1] = make_float4(s2, 0.f, 0.f, 0.f);
    ad2[node] = d2;
}

// Layer 2 gather on packed h' (8-dim), W2 per-node after normalization, fused log_softmax.
__global__ __launch_bounds__(256) void k_gather16(const int* __restrict__ row_ptr,
    const int* __restrict__ colsrc, const float4* __restrict__ featpk, const float* __restrict__ ad,
    const float* __restrict__ W2, const float* __restrict__ bias, float* __restrict__ outp, int n)
{
    __shared__ float w2s[128], bv[16];
    if (threadIdx.x < 128) w2s[threadIdx.x] = W2[threadIdx.x];
    else if (threadIdx.x < 144) bv[threadIdx.x - 128] = bias[threadIdx.x - 128];
    __syncthreads();

    int wid  = (blockIdx.x * 256 + threadIdx.x) >> 6;
    int lane = threadIdx.x & 63;
    int l16  = lane & 15;
    int node = wid * 4 + (lane >> 4);
    bool active = node < n;

    int start = 0, end = 0;
    float adn = 0.f;
    if (active) { start = row_ptr[node]; end = row_ptr[node + 1]; adn = ad[node]; }

    float wsum = 0.f, acc[8];
#pragma unroll
    for (int k = 0; k < 8; ++k) acc[k] = 0.f;

    for (int i = start + l16; i < end; i += 16) {
        int s = colsrc[i];
        union { float4 fv; __half2 h[4]; } u;
        u.fv = featpk[2 * (size_t)s];
        float4 meta = featpk[2 * (size_t)s + 1];
        float t = meta.x + adn;
        float w = __expf(t > 0.f ? t : NEG * t);
        wsum += w;
#pragma unroll
        for (int q = 0; q < 4; ++q) {
            float2 hv = __half22float2(u.h[q]);
            acc[2 * q + 0] += w * hv.x;
            acc[2 * q + 1] += w * hv.y;
        }
    }
#pragma unroll
    for (int off = 8; off; off >>= 1) {
        wsum += __shfl_xor(wsum, off, 64);
#pragma unroll
        for (int k = 0; k < 8; ++k) acc[k] += __shfl_xor(acc[k], off, 64);
    }
    if (!active) return;

    float inv = wsum > 0.f ? 1.f / wsum : 0.f;
    float o = bv[l16];
#pragma unroll
    for (int k = 0; k < 8; ++k) o += (acc[k] * inv) * w2s[k * 16 + l16];
    float m = o;
#pragma unroll
    for (int off = 8; off; off >>= 1) m = fmaxf(m, __shfl_xor(m, off, 64));
    float se = __expf(o - m);
#pragma unroll
    for (int off = 8; off; off >>= 1) se += __shfl_xor(se, off, 64);
    float l = m + __logf(se);
    outp[(size_t)node * 16 + l16] = o - l;
}

// ============================ fallback: pure atomic path (fp32) ============================

__global__ __launch_bounds__(256) void k1_nodeF(const float* __restrict__ x,
    const float* __restrict__ W1, const float* __restrict__ a1s, const float* __restrict__ a1d,
    float* __restrict__ h1, float* __restrict__ as1, float* __restrict__ ad1, int n)
{
    __shared__ float wt[8 * 128];
    __shared__ float av[16];
    for (int i = threadIdx.x; i < 1024; i += 256) {
        int r = i >> 3, k = i & 7;
        wt[k * 128 + r] = W1[i];
    }
    if (threadIdx.x < 8)        av[threadIdx.x] = a1s[threadIdx.x];
    else if (threadIdx.x < 16)  av[threadIdx.x] = a1d[threadIdx.x - 8];
    __syncthreads();

    int lane = threadIdx.x & 31;
    int node = blockIdx.x * 8 + (threadIdx.x >> 5);
    if (node >= n) return;

    float4 xv = ((const float4*)(x + (size_t)node * 128))[lane];
    float p[8];
#pragma unroll
    for (int k = 0; k < 8; ++k) {
        float4 wv = ((const float4*)(wt + k * 128))[lane];
        p[k] = xv.x * wv.x + xv.y * wv.y + xv.z * wv.z + xv.w * wv.w;
    }
#pragma unroll
    for (int off = 16; off; off >>= 1)
#pragma unroll
        for (int k = 0; k < 8; ++k) p[k] += __shfl_down(p[k], off, 32);

    if (lane == 0) {
        float s = 0.f, d = 0.f;
#pragma unroll
        for (int k = 0; k < 8; ++k) {
            h1[(size_t)node * 8 + k] = p[k];
            s += p[k] * av[k];
            d += p[k] * av[8 + k];
        }
        as1[node] = s;
        ad1[node] = d;
    }
}

template <int F>
__global__ __launch_bounds__(256) void k_edge(const int* __restrict__ src, const int* __restrict__ dst,
    const float* __restrict__ as, const float* __restrict__ ad, const float* __restrict__ feat,
    float* __restrict__ denom, float* __restrict__ acc, int E)
{
    int e = blockIdx.x * 256 + threadIdx.x;
    if (e >= E) return;
    int s = src[e], d = dst[e];
    float t = as[s] + ad[d];
    float w = __expf(t > 0.f ? t : NEG * t);
    atomicAdd(denom + d, w);
    const float* fs = feat + (size_t)s * F;
    float* ac = acc + (size_t)d * F;
#pragma unroll
    for (int k = 0; k < F; ++k) atomicAdd(ac + k, w * fs[k]);
}

__global__ __launch_bounds__(256) void k3_node(const float* __restrict__ denom1,
    const float* __restrict__ acc1, const float* __restrict__ b1,
    const float* __restrict__ W2, const float* __restrict__ a2s, const float* __restrict__ a2d,
    float* __restrict__ g, float* __restrict__ as2, float* __restrict__ ad2, int n)
{
    __shared__ float w2[128];
    __shared__ float aa[32];
    __shared__ float bb[8];
    if (threadIdx.x < 128) w2[threadIdx.x] = W2[threadIdx.x];
    if (threadIdx.x >= 128 && threadIdx.x < 144) aa[threadIdx.x - 128] = a2s[threadIdx.x - 128];
    if (threadIdx.x >= 144 && threadIdx.x < 160) aa[16 + threadIdx.x - 144] = a2d[threadIdx.x - 144];
    if (threadIdx.x >= 160 && threadIdx.x < 168) bb[threadIdx.x - 160] = b1[threadIdx.x - 160];
    __syncthreads();

    int node = blockIdx.x * 256 + threadIdx.x;
    if (node >= n) return;
    float dn = denom1[node];
    float inv = dn > 0.f ? 1.f / dn : 0.f;
    float h[8];
#pragma unroll
    for (int k = 0; k < 8; ++k) {
        float v = acc1[(size_t)node * 8 + k] * inv + bb[k];
        h[k] = v > 0.f ? v : 0.f;
    }
    float s = 0.f, dd = 0.f;
#pragma unroll
    for (int c = 0; c < 16; ++c) {
        float gv = 0.f;
#pragma unroll
        for (int k = 0; k < 8; ++k) gv += h[k] * w2[k * 16 + c];
        g[(size_t)node * 16 + c] = gv;
        s += gv * aa[c];
        dd += gv * aa[16 + c];
    }
    as2[node] = s;
    ad2[node] = dd;
}

__global__ __launch_bounds__(256) void k5_final(const float* __restrict__ denom2,
    const float* __restrict__ acc2, const float* __restrict__ b2, float* __restrict__ out, int n)
{
    __shared__ float bb[16];
    if (threadIdx.x < 16) bb[threadIdx.x] = b2[threadIdx.x];
    __syncthreads();

    int node = blockIdx.x * 256 + threadIdx.x;
    if (node >= n) return;
    float dn = denom2[node];
    float inv = dn > 0.f ? 1.f / dn : 0.f;
    float o[16];
    float m = -1e30f;
#pragma unroll
    for (int c = 0; c < 16; ++c) {
        o[c] = acc2[(size_t)node * 16 + c] * inv + bb[c];
        m = fmaxf(m, o[c]);
    }
    float se = 0.f;
#pragma unroll
    for (int c = 0; c < 16; ++c) {
        o[c] -= m;
        se += __expf(o[c]);
    }
    float l = __logf(se);
#pragma unroll
    for (int c = 0; c < 16; ++c) out[(size_t)node * 16 + c] = o[c] - l;
}

// ============================ launch ============================

static inline char* align256(char* p) {
    return (char*)(((uintptr_t)p + 255) & ~(uintptr_t)255);
}

extern "C" void kernel_launch(void* const* d_in, const int* in_sizes, int n_in,
                              void* d_out, int out_size, void* d_ws, size_t ws_size,
                              hipStream_t stream)
{
    const float* x    = (const float*)d_in[0];
    const int*   eidx = (const int*)d_in[1];
    const float* W1   = (const float*)d_in[2];
    const float* a1s  = (const float*)d_in[3];
    const float* a1d  = (const float*)d_in[4];
    const float* b1   = (const float*)d_in[5];
    const float* W2   = (const float*)d_in[6];
    const float* a2s  = (const float*)d_in[7];
    const float* a2d  = (const float*)d_in[8];
    const float* b2   = (const float*)d_in[9];
    float* out = (float*)d_out;

    const int n = in_sizes[0] / 128;
    const int E = in_sizes[1] / 2;
    const int* src = eidx;
    const int* dst = eidx + E;
    const int NB = (n + BUCKN - 1) >> CSHIFT;
    const int NBLK = (E + CHUNK - 1) / CHUNK;

    // ---- tier-0: bucket-sort CSR (gmat/pbaseRel aliased into colsrc) + packed fp16 gathers ----
    {
        char* p = (char*)d_ws;
        char* p0 = p;
        unsigned* stage = (unsigned*)p;  p = align256(p + (size_t)E * 4);
        int* colsrc  = (int*)p;          p = align256(p + (size_t)E * 4);
        int* total   = (int*)p;          p = align256(p + (size_t)NB * 4);
        int* cptr    = (int*)p;          p = align256(p + (size_t)(NB + 1) * 4);
        int* row_ptr = (int*)p;          p = align256(p + (size_t)(n + 1) * 4);
        float4* h1pk  = (float4*)p;      p = align256(p + (size_t)n * 32);
        float4* h1ppk = (float4*)p;      p = align256(p + (size_t)n * 32);
        float* ad1   = (float*)p;        p = align256(p + (size_t)n * 4);
        float* ad2   = (float*)p;        p = align256(p + (size_t)n * 4);
        size_t needed = (size_t)(p - p0);

        int* gmat     = colsrc;                       // alias (dead before p2f)
        int* pbaseRel = (int*)align256((char*)(colsrc + (size_t)NBLK * NB));

        bool alias_ok = ((size_t)2 * NBLK * NB + 64) <= (size_t)E;

        if (n <= 131072 && NB <= MAXNB && alias_ok && ws_size >= needed) {
            k1_node<<<(n + 7) / 8, 256, 0, stream>>>(x, W1, a1s, a1d, h1pk, ad1, n);

            p1a<<<NBLK, 256, 0, stream>>>(dst, gmat, E, NB);
            pcol<<<NB, 256, 0, stream>>>(gmat, pbaseRel, total, NBLK, NB);
            ptot<<<1, 512, 0, stream>>>(total, cptr, row_ptr, NB, n, E);
            p1bW<<<NBLK, 256, 0, stream>>>(src, dst, gmat, cptr, pbaseRel, stage, E, NB);
            p2f<<<NB, 1024, 0, stream>>>(stage, cptr, colsrc, row_ptr, n);

            // 16 lanes per node, 4 nodes per wave
            const int gblocks = ((size_t)n * 16 + 255) / 256;
            k_gather8f<<<gblocks, 256, 0, stream>>>(row_ptr, colsrc, h1pk, ad1,
                                                    b1, W2, a2s, a2d, h1ppk, ad2, n);
            k_gather16<<<gblocks, 256, 0, stream>>>(row_ptr, colsrc, h1ppk, ad2, W2, b2, out, n);
            return;
        }
    }

    // ---- fallback: pure atomic path (fp32) ----
    {
        float* ws     = (float*)d_ws;
        float* denom1 = ws;
        float* acc1   = ws + (size_t)n;
        float* denom2 = ws + (size_t)9 * n;
        float* acc2   = ws + (size_t)10 * n;
        float* h1     = ws + (size_t)26 * n;
        float* as1    = ws + (size_t)34 * n;
        float* ad1    = ws + (size_t)35 * n;
        float* g      = ws + (size_t)36 * n;
        float* as2    = ws + (size_t)52 * n;
        float* ad2    = ws + (size_t)53 * n;

        hipMemsetAsync(ws, 0, (size_t)26 * n * sizeof(float), stream);
        k1_nodeF<<<(n + 7) / 8, 256, 0, stream>>>(x, W1, a1s, a1d, h1, as1, ad1, n);
        k_edge<8><<<(E + 255) / 256, 256, 0, stream>>>(src, dst, as1, ad1, h1, denom1, acc1, E);
        k3_node<<<(n + 255) / 256, 256, 0, stream>>>(denom1, acc1, b1, W2, a2s, a2d, g, as2, ad2, n);
        k_edge<16><<<(E + 255) / 256, 256, 0, stream>>>(src, dst, as2, ad2, g, denom2, acc2, E);
        k5_final<<<(n + 255) / 256, 256, 0, stream>>>(denom2, acc2, b2, out, n);
    }
}

// Round 21
// 180.233 us; speedup vs baseline: 1.2002x; 1.0515x over previous
//
#include <hip/hip_runtime.h>
#include <hip/hip_fp16.h>
#include <math.h>
#include <stdint.h>

#define NEG 0.2f
#define CSHIFT 9
#define BUCKN (1 << CSHIFT)     // 512 nodes per coarse bucket
#define MAXNB 256               // NB <= 256 for n <= 131072 (CSHIFT=9)
#define CHUNK 4096
#define FBUF2 34816             // full-span staged colsrc (mean 32.6K @ n=100k/E=6.4M)

// ============================ node transform (packed 32B rows: 8 fp16 h | fp32 alpha_s | pad) ============================

__global__ __launch_bounds__(256) void k1_node(const float* __restrict__ x,
    const float* __restrict__ W1, const float* __restrict__ a1s, const float* __restrict__ a1d,
    float4* __restrict__ h1pk, float* __restrict__ ad1, int n)
{
    __shared__ float wt[8 * 128];
    __shared__ float av[16];
    for (int i = threadIdx.x; i < 1024; i += 256) {
        int r = i >> 3, k = i & 7;
        wt[k * 128 + r] = W1[i];
    }
    if (threadIdx.x < 8)        av[threadIdx.x] = a1s[threadIdx.x];
    else if (threadIdx.x < 16)  av[threadIdx.x] = a1d[threadIdx.x - 8];
    __syncthreads();

    int lane = threadIdx.x & 31;
    int node = blockIdx.x * 8 + (threadIdx.x >> 5);
    if (node >= n) return;

    float4 xv = ((const float4*)(x + (size_t)node * 128))[lane];
    float p[8];
#pragma unroll
    for (int k = 0; k < 8; ++k) {
        float4 wv = ((const float4*)(wt + k * 128))[lane];
        p[k] = xv.x * wv.x + xv.y * wv.y + xv.z * wv.z + xv.w * wv.w;
    }
#pragma unroll
    for (int off = 16; off; off >>= 1)
#pragma unroll
        for (int k = 0; k < 8; ++k) p[k] += __shfl_down(p[k], off, 32);

    if (lane == 0) {
        float s = 0.f, d = 0.f;
        union { float4 f; __half2 h[4]; } u;
#pragma unroll
        for (int k = 0; k < 8; ++k) {
            s += p[k] * av[k];
            d += p[k] * av[8 + k];
        }
#pragma unroll
        for (int q = 0; q < 4; ++q) u.h[q] = __floats2half2_rn(p[2 * q], p[2 * q + 1]);
        h1pk[2 * (size_t)node]     = u.f;                        // 16B fp16 h row
        h1pk[2 * (size_t)node + 1] = make_float4(s, 0.f, 0.f, 0.f);  // alpha_s
        ad1[node] = d;
    }
}

// ============================ bucket-sort CSR build (all-parallel, atomic-free) ============================

__global__ __launch_bounds__(256) void p1a(const int* __restrict__ dst, int* __restrict__ gmat,
                                           int E, int NB)
{
    __shared__ int h[MAXNB];
    for (int i = threadIdx.x; i < NB; i += 256) h[i] = 0;
    __syncthreads();
    int base = blockIdx.x * CHUNK;
    int end = base + CHUNK; if (end > E) end = E;
    for (int i = base + threadIdx.x; i < end; i += 256)
        atomicAdd(&h[dst[i] >> CSHIFT], 1);
    __syncthreads();
    int* row = gmat + (size_t)blockIdx.x * NB;
    for (int i = threadIdx.x; i < NB; i += 256) row[i] = h[i];
}

__global__ __launch_bounds__(256) void pcol(const int* __restrict__ gmat, int* __restrict__ pbaseRel,
    int* __restrict__ total, int NBLK, int NB)
{
    __shared__ int wsum[4];
    int b = blockIdx.x;
    int tid = threadIdx.x;
    int chunk = (NBLK + 255) >> 8;
    int k0 = tid * chunk;
    int s = 0;
    for (int j = 0; j < chunk; ++j) {
        int k = k0 + j;
        if (k < NBLK) s += gmat[(size_t)k * NB + b];
    }
    int lane = tid & 63, w = tid >> 6;
    int sc = s;
#pragma unroll
    for (int off = 1; off < 64; off <<= 1) {
        int t = __shfl_up(sc, off, 64);
        if (lane >= off) sc += t;
    }
    if (lane == 63) wsum[w] = sc;
    __syncthreads();
    if (tid == 0) { int a = 0; for (int i = 0; i < 4; ++i) { int t = wsum[i]; wsum[i] = a; a += t; } }
    __syncthreads();
    int run = sc - s + wsum[w];
    for (int j = 0; j < chunk; ++j) {
        int k = k0 + j;
        if (k < NBLK) {
            int gv = gmat[(size_t)k * NB + b];
            pbaseRel[(size_t)k * NB + b] = run;
            run += gv;
        }
    }
    if (tid == 255) total[b] = run;
}

// scan bucket totals -> cptr (single block, chunked over NB)
__global__ __launch_bounds__(512) void ptot(const int* __restrict__ total, int* __restrict__ cptr,
                                            int* __restrict__ row_ptr, int NB, int n, int E)
{
    __shared__ int wsum[8];
    int tid = threadIdx.x;
    int chunk = (NB + 511) >> 9;
    int k0 = tid * chunk;
    int s = 0;
    for (int j = 0; j < chunk; ++j) {
        int k = k0 + j;
        if (k < NB) s += total[k];
    }
    int lane = tid & 63, w = tid >> 6;
    int sc = s;
#pragma unroll
    for (int off = 1; off < 64; off <<= 1) {
        int t = __shfl_up(sc, off, 64);
        if (lane >= off) sc += t;
    }
    if (lane == 63) wsum[w] = sc;
    __syncthreads();
    if (tid == 0) { int a = 0; for (int i = 0; i < 8; ++i) { int t = wsum[i]; wsum[i] = a; a += t; } }
    __syncthreads();
    int run = sc - s + wsum[w];
    for (int j = 0; j < chunk; ++j) {
        int k = k0 + j;
        if (k < NB) { cptr[k] = run; run += total[k]; }
    }
    if (tid == 0) { cptr[NB] = E; row_ptr[n] = E; }
}

// pass 1b: LDS write-combining; 512 threads, u8 bucket tags (NB <= 256 guarded at launch).
__global__ __launch_bounds__(512) void p1bW(const int* __restrict__ src, const int* __restrict__ dst,
    const int* __restrict__ gmat, const int* __restrict__ cptr, const int* __restrict__ pbaseRel,
    unsigned* __restrict__ stage, int E, int NB)
{
    __shared__ int lbase[MAXNB], bbase[MAXNB], ccur[MAXNB];
    __shared__ unsigned bufp[CHUNK];
    __shared__ unsigned char bufb[CHUNK];
    __shared__ int wsum[8];
    int tid = threadIdx.x;
    const int* grow = gmat + (size_t)blockIdx.x * NB;
    const int* prow = pbaseRel + (size_t)blockIdx.x * NB;

    int base = blockIdx.x * CHUNK;
    int end = base + CHUNK; if (end > E) end = E;
    int cnt = end - base;

    // single-round exclusive scan of this block's histogram row (512 threads >= NB)
    int v = (tid < NB) ? grow[tid] : 0;
    int lane = tid & 63, w = tid >> 6;
    int sc = v;
#pragma unroll
    for (int off = 1; off < 64; off <<= 1) {
        int t = __shfl_up(sc, off, 64);
        if (lane >= off) sc += t;
    }
    if (lane == 63) wsum[w] = sc;
    __syncthreads();
    if (tid == 0) { int a = 0; for (int i = 0; i < 8; ++i) { int t = wsum[i]; wsum[i] = a; a += t; } }
    __syncthreads();
    if (tid < NB) {
        lbase[tid] = sc - v + wsum[w];
        bbase[tid] = cptr[tid] + prow[tid];
        ccur[tid] = 0;
    }
    __syncthreads();

    // LDS scatter (random LDS, cheap); pack carries 9 fine bits
    for (int i = base + tid; i < end; i += 512) {
        int d = dst[i];
        int b = d >> CSHIFT;
        int off = atomicAdd(&ccur[b], 1);
        int pos = lbase[b] + off;
        bufp[pos] = ((unsigned)(d & (BUCKN - 1)) << 17) | (unsigned)src[i];
        bufb[pos] = (unsigned char)b;
    }
    __syncthreads();

    // flush: consecutive local positions within a bucket -> consecutive global (runs of ~21)
    for (int i = tid; i < cnt; i += 512) {
        int b = bufb[i];
        stage[bbase[b] + (i - lbase[b])] = bufp[i];
    }
}

// pass 2 (full-span): one block per coarse bucket; histogram + scan + LDS-staged coalesced emit.
__global__ __launch_bounds__(1024) void p2f(const unsigned* __restrict__ stage,
    const int* __restrict__ cptr, int* __restrict__ colsrc, int* __restrict__ row_ptr, int n)
{
    int b = blockIdx.x;
    int nbase = b << CSHIFT;
    int NN = n - nbase; if (NN > BUCKN) NN = BUCKN;
    __shared__ int h[BUCKN], cc[BUCKN];  // 4 KB
    __shared__ int wsum[8];
    __shared__ int buf[FBUF2];           // 136 KB staged colsrc image
    int tid = threadIdx.x;
    if (tid < BUCKN) { h[tid] = 0; cc[tid] = 0; }
    __syncthreads();
    int s0 = cptr[b], s1 = cptr[b + 1];
    int span = s1 - s0;

    // 1st pass: 512-bin histogram (streaming read)
    for (int i = s0 + tid; i < s1; i += 1024)
        atomicAdd(&h[stage[i] >> 17], 1);
    __syncthreads();

    // exclusive scan of 512 bins (first 8 waves own one bin each)
    int v = (tid < BUCKN) ? h[tid] : 0;
    int lane = tid & 63, w = tid >> 6;
    int sc = v;
#pragma unroll
    for (int off = 1; off < 64; off <<= 1) {
        int t = __shfl_up(sc, off, 64);
        if (lane >= off) sc += t;
    }
    if (tid < BUCKN && lane == 63) wsum[w] = sc;
    __syncthreads();
    if (tid == 0) { int a = 0; for (int i = 0; i < 8; ++i) { int t = wsum[i]; wsum[i] = a; a += t; } }
    __syncthreads();
    if (tid < BUCKN) {
        int excl = sc - v + wsum[w];
        h[tid] = excl;                    // within-bucket exclusive offset
        if (tid < NN) row_ptr[nbase + tid] = s0 + excl;
    }
    __syncthreads();

    if (span <= FBUF2) {
        // 2nd pass: scatter into LDS (stage re-read is L2-resident), flush coalesced
        for (int i = s0 + tid; i < s1; i += 1024) {
            unsigned p = stage[i];
            int f = p >> 17;
            int off = atomicAdd(&cc[f], 1);
            buf[h[f] + off] = (int)(p & 0x1FFFFu);
        }
        __syncthreads();
        for (int i = tid; i < span; i += 1024)
            colsrc[s0 + i] = buf[i];
    } else {
        // pathological bucket: direct scatter (correct for any distribution)
        for (int i = s0 + tid; i < s1; i += 1024) {
            unsigned p = stage[i];
            int f = p >> 17;
            int off = atomicAdd(&cc[f], 1);
            colsrc[s0 + h[f] + off] = (int)(p & 0x1FFFFu);
        }
    }
}

// ============================ gathers (packed 32B rows, 16 lanes/node, 4 nodes/wave) ============================

// Layer 1 gather -> h' packed (16B fp16 h' | fp32 as2 | pad); ad2 separate.
// as2/ad2 via precomputed W2@a2s / W2@a2d (aggregation commutes with W2).
__global__ __launch_bounds__(256) void k_gather8f(const int* __restrict__ row_ptr,
    const int* __restrict__ colsrc, const float4* __restrict__ featpk, const float* __restrict__ ad,
    const float* __restrict__ b1, const float* __restrict__ W2,
    const float* __restrict__ a2s, const float* __restrict__ a2d,
    float4* __restrict__ outpk, float* __restrict__ ad2, int n)
{
    __shared__ float w2as[8], w2ad[8], b1v[8];
    if (threadIdx.x < 8) {
        float s = 0.f, d = 0.f;
#pragma unroll
        for (int c = 0; c < 16; ++c) {
            float wv = W2[threadIdx.x * 16 + c];
            s += wv * a2s[c];
            d += wv * a2d[c];
        }
        w2as[threadIdx.x] = s;
        w2ad[threadIdx.x] = d;
        b1v[threadIdx.x] = b1[threadIdx.x];
    }
    __syncthreads();

    int wid  = (blockIdx.x * 256 + threadIdx.x) >> 6;
    int lane = threadIdx.x & 63;
    int l16  = lane & 15;
    int node = wid * 4 + (lane >> 4);
    bool active = node < n;

    int start = 0, end = 0;
    float adn = 0.f;
    if (active) { start = row_ptr[node]; end = row_ptr[node + 1]; adn = ad[node]; }

    float wsum = 0.f, acc[8];
#pragma unroll
    for (int k = 0; k < 8; ++k) acc[k] = 0.f;

    for (int i = start + l16; i < end; i += 16) {
        int s = colsrc[i];
        union { float4 fv; __half2 h[4]; } u;
        u.fv = featpk[2 * (size_t)s];            // 16B fp16 h row
        float4 meta = featpk[2 * (size_t)s + 1]; // alpha_s in .x (same 32B line)
        float t = meta.x + adn;
        float w = __expf(t > 0.f ? t : NEG * t); // max-shift skipped: |t| small, exact ratio
        wsum += w;
#pragma unroll
        for (int q = 0; q < 4; ++q) {
            float2 hv = __half22float2(u.h[q]);
            acc[2 * q + 0] += w * hv.x;
            acc[2 * q + 1] += w * hv.y;
        }
    }
#pragma unroll
    for (int off = 8; off; off >>= 1) {
        wsum += __shfl_xor(wsum, off, 64);
#pragma unroll
        for (int k = 0; k < 8; ++k) acc[k] += __shfl_xor(acc[k], off, 64);
    }
    if (!active || l16 != 0) return;

    float inv = wsum > 0.f ? 1.f / wsum : 0.f;
    float h[8], s2 = 0.f, d2 = 0.f;
    union { float4 f; __half2 hh[4]; } u;
#pragma unroll
    for (int k = 0; k < 8; ++k) {
        float v = acc[k] * inv + b1v[k];
        h[k] = v > 0.f ? v : 0.f;
        s2 += h[k] * w2as[k];
        d2 += h[k] * w2ad[k];
    }
#pragma unroll
    for (int q = 0; q < 4; ++q) u.hh[q] = __floats2half2_rn(h[2 * q], h[2 * q + 1]);
    outpk[2 * (size_t)node]     = u.f;
    outpk[2 * (size_t)node + 1] = make_float4(s2, 0.f, 0.f, 0.f);
    ad2[node] = d2;
}

// Layer 2 gather on packed h' (8-dim), W2 per-node after normalization, fused log_softmax.
__global__ __launch_bounds__(256) void k_gather16(const int* __restrict__ row_ptr,
    const int* __restrict__ colsrc, const float4* __restrict__ featpk, const float* __restrict__ ad,
    const float* __restrict__ W2, const float* __restrict__ bias, float* __restrict__ outp, int n)
{
    __shared__ float w2s[128], bv[16];
    if (threadIdx.x < 128) w2s[threadIdx.x] = W2[threadIdx.x];
    else if (threadIdx.x < 144) bv[threadIdx.x - 128] = bias[threadIdx.x - 128];
    __syncthreads();

    int wid  = (blockIdx.x * 256 + threadIdx.x) >> 6;
    int lane = threadIdx.x & 63;
    int l16  = lane & 15;
    int node = wid * 4 + (lane >> 4);
    bool active = node < n;

    int start = 0, end = 0;
    float adn = 0.f;
    if (active) { start = row_ptr[node]; end = row_ptr[node + 1]; adn = ad[node]; }

    float wsum = 0.f, acc[8];
#pragma unroll
    for (int k = 0; k < 8; ++k) acc[k] = 0.f;

    for (int i = start + l16; i < end; i += 16) {
        int s = colsrc[i];
        union { float4 fv; __half2 h[4]; } u;
        u.fv = featpk[2 * (size_t)s];
        float4 meta = featpk[2 * (size_t)s + 1];
        float t = meta.x + adn;
        float w = __expf(t > 0.f ? t : NEG * t);
        wsum += w;
#pragma unroll
        for (int q = 0; q < 4; ++q) {
            float2 hv = __half22float2(u.h[q]);
            acc[2 * q + 0] += w * hv.x;
            acc[2 * q + 1] += w * hv.y;
        }
    }
#pragma unroll
    for (int off = 8; off; off >>= 1) {
        wsum += __shfl_xor(wsum, off, 64);
#pragma unroll
        for (int k = 0; k < 8; ++k) acc[k] += __shfl_xor(acc[k], off, 64);
    }
    if (!active) return;

    float inv = wsum > 0.f ? 1.f / wsum : 0.f;
    float o = bv[l16];
#pragma unroll
    for (int k = 0; k < 8; ++k) o += (acc[k] * inv) * w2s[k * 16 + l16];
    float m = o;
#pragma unroll
    for (int off = 8; off; off >>= 1) m = fmaxf(m, __shfl_xor(m, off, 64));
    float se = __expf(o - m);
#pragma unroll
    for (int off = 8; off; off >>= 1) se += __shfl_xor(se, off, 64);
    float l = m + __logf(se);
    outp[(size_t)node * 16 + l16] = o - l;
}

// ============================ fallback: pure atomic path (fp32) ============================

__global__ __launch_bounds__(256) void k1_nodeF(const float* __restrict__ x,
    const float* __restrict__ W1, const float* __restrict__ a1s, const float* __restrict__ a1d,
    float* __restrict__ h1, float* __restrict__ as1, float* __restrict__ ad1, int n)
{
    __shared__ float wt[8 * 128];
    __shared__ float av[16];
    for (int i = threadIdx.x; i < 1024; i += 256) {
        int r = i >> 3, k = i & 7;
        wt[k * 128 + r] = W1[i];
    }
    if (threadIdx.x < 8)        av[threadIdx.x] = a1s[threadIdx.x];
    else if (threadIdx.x < 16)  av[threadIdx.x] = a1d[threadIdx.x - 8];
    __syncthreads();

    int lane = threadIdx.x & 31;
    int node = blockIdx.x * 8 + (threadIdx.x >> 5);
    if (node >= n) return;

    float4 xv = ((const float4*)(x + (size_t)node * 128))[lane];
    float p[8];
#pragma unroll
    for (int k = 0; k < 8; ++k) {
        float4 wv = ((const float4*)(wt + k * 128))[lane];
        p[k] = xv.x * wv.x + xv.y * wv.y + xv.z * wv.z + xv.w * wv.w;
    }
#pragma unroll
    for (int off = 16; off; off >>= 1)
#pragma unroll
        for (int k = 0; k < 8; ++k) p[k] += __shfl_down(p[k], off, 32);

    if (lane == 0) {
        float s = 0.f, d = 0.f;
#pragma unroll
        for (int k = 0; k < 8; ++k) {
            h1[(size_t)node * 8 + k] = p[k];
            s += p[k] * av[k];
            d += p[k] * av[8 + k];
        }
        as1[node] = s;
        ad1[node] = d;
    }
}

template <int F>
__global__ __launch_bounds__(256) void k_edge(const int* __restrict__ src, const int* __restrict__ dst,
    const float* __restrict__ as, const float* __restrict__ ad, const float* __restrict__ feat,
    float* __restrict__ denom, float* __restrict__ acc, int E)
{
    int e = blockIdx.x * 256 + threadIdx.x;
    if (e >= E) return;
    int s = src[e], d = dst[e];
    float t = as[s] + ad[d];
    float w = __expf(t > 0.f ? t : NEG * t);
    atomicAdd(denom + d, w);
    const float* fs = feat + (size_t)s * F;
    float* ac = acc + (size_t)d * F;
#pragma unroll
    for (int k = 0; k < F; ++k) atomicAdd(ac + k, w * fs[k]);
}

__global__ __launch_bounds__(256) void k3_node(const float* __restrict__ denom1,
    const float* __restrict__ acc1, const float* __restrict__ b1,
    const float* __restrict__ W2, const float* __restrict__ a2s, const float* __restrict__ a2d,
    float* __restrict__ g, float* __restrict__ as2, float* __restrict__ ad2, int n)
{
    __shared__ float w2[128];
    __shared__ float aa[32];
    __shared__ float bb[8];
    if (threadIdx.x < 128) w2[threadIdx.x] = W2[threadIdx.x];
    if (threadIdx.x >= 128 && threadIdx.x < 144) aa[threadIdx.x - 128] = a2s[threadIdx.x - 128];
    if (threadIdx.x >= 144 && threadIdx.x < 160) aa[16 + threadIdx.x - 144] = a2d[threadIdx.x - 144];
    if (threadIdx.x >= 160 && threadIdx.x < 168) bb[threadIdx.x - 160] = b1[threadIdx.x - 160];
    __syncthreads();

    int node = blockIdx.x * 256 + threadIdx.x;
    if (node >= n) return;
    float dn = denom1[node];
    float inv = dn > 0.f ? 1.f / dn : 0.f;
    float h[8];
#pragma unroll
    for (int k = 0; k < 8; ++k) {
        float v = acc1[(size_t)node * 8 + k] * inv + bb[k];
        h[k] = v > 0.f ? v : 0.f;
    }
    float s = 0.f, dd = 0.f;
#pragma unroll
    for (int c = 0; c < 16; ++c) {
        float gv = 0.f;
#pragma unroll
        for (int k = 0; k < 8; ++k) gv += h[k] * w2[k * 16 + c];
        g[(size_t)node * 16 + c] = gv;
        s += gv * aa[c];
        dd += gv * aa[16 + c];
    }
    as2[node] = s;
    ad2[node] = dd;
}

__global__ __launch_bounds__(256) void k5_final(const float* __restrict__ denom2,
    const float* __restrict__ acc2, const float* __restrict__ b2, float* __restrict__ out, int n)
{
    __shared__ float bb[16];
    if (threadIdx.x < 16) bb[threadIdx.x] = b2[threadIdx.x];
    __syncthreads();

    int node = blockIdx.x * 256 + threadIdx.x;
    if (node >= n) return;
    float dn = denom2[node];
    float inv = dn > 0.f ? 1.f / dn : 0.f;
    float o[16];
    float m = -1e30f;
#pragma unroll
    for (int c = 0; c < 16; ++c) {
        o[c] = acc2[(size_t)node * 16 + c] * inv + bb[c];
        m = fmaxf(m, o[c]);
    }
    float se = 0.f;
#pragma unroll
    for (int c = 0; c < 16; ++c) {
        o[c] -= m;
        se += __expf(o[c]);
    }
    float l = __logf(se);
#pragma unroll
    for (int c = 0; c < 16; ++c) out[(size_t)node * 16 + c] = o[c] - l;
}

// ============================ launch ============================

static inline char* align256(char* p) {
    return (char*)(((uintptr_t)p + 255) & ~(uintptr_t)255);
}

extern "C" void kernel_launch(void* const* d_in, const int* in_sizes, int n_in,
                              void* d_out, int out_size, void* d_ws, size_t ws_size,
                              hipStream_t stream)
{
    const float* x    = (const float*)d_in[0];
    const int*   eidx = (const int*)d_in[1];
    const float* W1   = (const float*)d_in[2];
    const float* a1s  = (const float*)d_in[3];
    const float* a1d  = (const float*)d_in[4];
    const float* b1   = (const float*)d_in[5];
    const float* W2   = (const float*)d_in[6];
    const float* a2s  = (const float*)d_in[7];
    const float* a2d  = (const float*)d_in[8];
    const float* b2   = (const float*)d_in[9];
    float* out = (float*)d_out;

    const int n = in_sizes[0] / 128;
    const int E = in_sizes[1] / 2;
    const int* src = eidx;
    const int* dst = eidx + E;
    const int NB = (n + BUCKN - 1) >> CSHIFT;
    const int NBLK = (E + CHUNK - 1) / CHUNK;

    // ---- tier-0: bucket-sort CSR (gmat/pbaseRel aliased into colsrc) + packed fp16 gathers ----
    {
        char* p = (char*)d_ws;
        char* p0 = p;
        unsigned* stage = (unsigned*)p;  p = align256(p + (size_t)E * 4);
        int* colsrc  = (int*)p;          p = align256(p + (size_t)E * 4);
        int* total   = (int*)p;          p = align256(p + (size_t)NB * 4);
        int* cptr    = (int*)p;          p = align256(p + (size_t)(NB + 1) * 4);
        int* row_ptr = (int*)p;          p = align256(p + (size_t)(n + 1) * 4);
        float4* h1pk  = (float4*)p;      p = align256(p + (size_t)n * 32);
        float4* h1ppk = (float4*)p;      p = align256(p + (size_t)n * 32);
        float* ad1   = (float*)p;        p = align256(p + (size_t)n * 4);
        float* ad2   = (float*)p;        p = align256(p + (size_t)n * 4);
        size_t needed = (size_t)(p - p0);

        int* gmat     = colsrc;                       // alias (dead before p2f)
        int* pbaseRel = (int*)align256((char*)(colsrc + (size_t)NBLK * NB));

        bool alias_ok = ((size_t)2 * NBLK * NB + 64) <= (size_t)E;

        if (n <= 131072 && NB <= MAXNB && alias_ok && ws_size >= needed) {
            k1_node<<<(n + 7) / 8, 256, 0, stream>>>(x, W1, a1s, a1d, h1pk, ad1, n);

            p1a<<<NBLK, 256, 0, stream>>>(dst, gmat, E, NB);
            pcol<<<NB, 256, 0, stream>>>(gmat, pbaseRel, total, NBLK, NB);
            ptot<<<1, 512, 0, stream>>>(total, cptr, row_ptr, NB, n, E);
            p1bW<<<NBLK, 512, 0, stream>>>(src, dst, gmat, cptr, pbaseRel, stage, E, NB);
            p2f<<<NB, 1024, 0, stream>>>(stage, cptr, colsrc, row_ptr, n);

            // 16 lanes per node, 4 nodes per wave
            const int gblocks = ((size_t)n * 16 + 255) / 256;
            k_gather8f<<<gblocks, 256, 0, stream>>>(row_ptr, colsrc, h1pk, ad1,
                                                    b1, W2, a2s, a2d, h1ppk, ad2, n);
            k_gather16<<<gblocks, 256, 0, stream>>>(row_ptr, colsrc, h1ppk, ad2, W2, b2, out, n);
            return;
        }
    }

    // ---- fallback: pure atomic path (fp32) ----
    {
        float* ws     = (float*)d_ws;
        float* denom1 = ws;
        float* acc1   = ws + (size_t)n;
        float* denom2 = ws + (size_t)9 * n;
        float* acc2   = ws + (size_t)10 * n;
        float* h1     = ws + (size_t)26 * n;
        float* as1    = ws + (size_t)34 * n;
        float* ad1    = ws + (size_t)35 * n;
        float* g      = ws + (size_t)36 * n;
        float* as2    = ws + (size_t)52 * n;
        float* ad2    = ws + (size_t)53 * n;

        hipMemsetAsync(ws, 0, (size_t)26 * n * sizeof(float), stream);
        k1_nodeF<<<(n + 7) / 8, 256, 0, stream>>>(x, W1, a1s, a1d, h1, as1, ad1, n);
        k_edge<8><<<(E + 255) / 256, 256, 0, stream>>>(src, dst, as1, ad1, h1, denom1, acc1, E);
        k3_node<<<(n + 255) / 256, 256, 0, stream>>>(denom1, acc1, b1, W2, a2s, a2d, g, as2, ad2, n);
        k_edge<16><<<(E + 255) / 256, 256, 0, stream>>>(src, dst, as2, ad2, g, denom2, acc2, E);
        k5_final<<<(n + 255) / 256, 256, 0, stream>>>(denom2, acc2, b2, out, n);
    }
}